// Round 13
// baseline (358.415 us; speedup 1.0000x reference)
//
#include <hip/hip_runtime.h>
#include <hip/hip_bf16.h>

typedef __attribute__((ext_vector_type(4))) float float4v;
typedef __attribute__((ext_vector_type(8))) short short8v;
typedef __attribute__((ext_vector_type(4))) unsigned int uint4v;

__device__ __forceinline__ unsigned short f2bf(float f) {
  __hip_bfloat16 h = __float2bfloat16(f);
  return __builtin_bit_cast(unsigned short, h);
}
__device__ __forceinline__ unsigned int pk2(float a, float b) {
  return (unsigned int)f2bf(a) | ((unsigned int)f2bf(b) << 16);
}

// Fused one-time pass: feat f32 -> bf16 table + new_point copy.
__global__ __launch_bounds__(256) void td_prep(const float* __restrict__ feat,
                                               unsigned short* __restrict__ fb,
                                               int total8,
                                               const float* __restrict__ point,
                                               const int* __restrict__ sidx,
                                               float* __restrict__ newp, int m,
                                               int prepBlocks) {
  if ((int)blockIdx.x < prepBlocks) {
    int i = blockIdx.x * 256 + threadIdx.x;
    if (i < total8) {
      const float4v a = *(const float4v*)(feat + (size_t)i * 8);
      const float4v c = *(const float4v*)(feat + (size_t)i * 8 + 4);
      uint4v u;
      u[0] = pk2(a[0], a[1]); u[1] = pk2(a[2], a[3]);
      u[2] = pk2(c[0], c[1]); u[3] = pk2(c[2], c[3]);
      *(uint4v*)(fb + (size_t)i * 8) = u;
    }
  } else {
    int i = (blockIdx.x - prepBlocks) * 256 + threadIdx.x;
    if (i < m) {
      unsigned s = (unsigned)sidx[i];
      newp[(size_t)i * 3 + 0] = point[s * 3u + 0];
      newp[(size_t)i * 3 + 1] = point[s * 3u + 1];
      newp[(size_t)i * 3 + 2] = point[s * 3u + 2];
    }
  }
}

#define MFMA16 __builtin_amdgcn_mfma_f32_16x16x32_bf16

// td_main, NO-LDS design: M=16 rows of one MFMA = the k=16 neighbors of ONE
// sampled point. A-fragment (lane l15=row, k=lg*8..) = fb[knn[p][l15]][lg*8..]
// = one 16B gather load per lane -> fragments built directly in registers.
// No LDS, no barriers; 4 waves channel-split (redundant gathers hit L1/L2).
// Natural footprint is 64 VGPR (R12 measured, no cap pressure, no persistent
// acc) -> 8 blocks/CU fits the 512/8=64 budget: 32 waves/CU of pure TLP.
__global__ __launch_bounds__(256, 8) void td_main(
    const float* __restrict__ point, const float* __restrict__ feat,
    const unsigned short* __restrict__ fb, const float* __restrict__ W,
    const float* __restrict__ gamma,
    const int* __restrict__ sample_idx, const int* __restrict__ knn_idx,
    float* __restrict__ ymax_out, float* __restrict__ ymin_out,
    float* __restrict__ partials, int nTiles, int has_ymin, int use_fb)
{
  const int tid  = threadIdx.x;
  const int lane = tid & 63;
  const int wv   = tid >> 6;        // wave -> output channels wv*32..+31
  const int l15  = lane & 15;       // row within MFMA tile = neighbor index
  const int lg   = (lane >> 4) & 3; // k-group
  const int G    = gridDim.x;
  const int t0   = blockIdx.x;

  // B fragments direct from global W (bf16-rounded), permuted K.
  short8v bfrag[2][3];
  #pragma unroll
  for (int ni = 0; ni < 2; ++ni) {
    const int d = wv * 32 + ni * 16 + l15;
    #pragma unroll
    for (int kk = 0; kk < 3; ++kk) {
      short8v bf;
      #pragma unroll
      for (int j = 0; j < 8; ++j) {
        int c = kk * 32 + (lg << 3) + j;
        float v = 0.f;
        if (c < 64)      v = W[(3 + c) * 128 + d];
        else if (c < 67) v = W[(c - 64) * 128 + d];
        bf[j] = (short)f2bf(v);
      }
      bfrag[ni][kk] = bf;
    }
  }
  const float gva = gamma[wv * 32 + l15];
  const float gvb = gamma[wv * 32 + 16 + l15];
  const bool  do_min = has_ymin && (__ballot((gva < 0.f) || (gvb < 0.f)) != 0ull);

  float sum0 = 0.f, sum1 = 0.f, sq0 = 0.f, sq1 = 0.f;

  // indices for current tile (prefetched one tile ahead in steady state)
  int gc0 = 0, gc1 = 0, gc2 = 0, gc3 = 0;   // knn row per mi (this lane's l15-row)
  int sc0 = 0, sc1 = 0, sc2 = 0, sc3 = 0;   // sample idx per mi (uniform)
  if (t0 < nTiles) {
    gc0 = knn_idx[t0 * 64 +  0 + l15];
    gc1 = knn_idx[t0 * 64 + 16 + l15];
    gc2 = knn_idx[t0 * 64 + 32 + l15];
    gc3 = knn_idx[t0 * 64 + 48 + l15];
    sc0 = sample_idx[t0 * 4 + 0]; sc1 = sample_idx[t0 * 4 + 1];
    sc2 = sample_idx[t0 * 4 + 2]; sc3 = sample_idx[t0 * 4 + 3];
  }

  for (int t = t0; t < nTiles; t += G) {
    // ---- issue all feat-fragment gathers (8 x 16B per lane) ----
    uint4v f00, f01, f02, f03, f10, f11, f12, f13;
    if (use_fb) {
      const unsigned short* r0 = fb + ((size_t)(unsigned)gc0 << 6) + (lg << 3);
      const unsigned short* r1 = fb + ((size_t)(unsigned)gc1 << 6) + (lg << 3);
      const unsigned short* r2 = fb + ((size_t)(unsigned)gc2 << 6) + (lg << 3);
      const unsigned short* r3 = fb + ((size_t)(unsigned)gc3 << 6) + (lg << 3);
      f00 = *(const uint4v*)(r0); f10 = *(const uint4v*)(r0 + 32);
      f01 = *(const uint4v*)(r1); f11 = *(const uint4v*)(r1 + 32);
      f02 = *(const uint4v*)(r2); f12 = *(const uint4v*)(r2 + 32);
      f03 = *(const uint4v*)(r3); f13 = *(const uint4v*)(r3 + 32);
    } else {
      // f32 fallback (ws too small for fb table) - per-mi load+convert
#define F32LD(FA, FB, GD)                                                      \
      {                                                                        \
        const float* r_ = feat + ((size_t)(unsigned)(GD) << 6) + (lg << 3);    \
        float4v x0_ = *(const float4v*)(r_),      x1_ = *(const float4v*)(r_ + 4);  \
        float4v y0_ = *(const float4v*)(r_ + 32), y1_ = *(const float4v*)(r_ + 36); \
        FA[0] = pk2(x0_[0], x0_[1]); FA[1] = pk2(x0_[2], x0_[3]);              \
        FA[2] = pk2(x1_[0], x1_[1]); FA[3] = pk2(x1_[2], x1_[3]);              \
        FB[0] = pk2(y0_[0], y0_[1]); FB[1] = pk2(y0_[2], y0_[3]);              \
        FB[2] = pk2(y1_[0], y1_[1]); FB[3] = pk2(y1_[2], y1_[3]);              \
      }
      F32LD(f00, f10, gc0) F32LD(f01, f11, gc1)
      F32LD(f02, f12, gc2) F32LD(f03, f13, gc3)
#undef F32LD
    }

    // ---- xyz diffs: only lg==0 lanes carry nonzero a2 elements ----
    float dx0 = 0, dy0 = 0, dz0 = 0, dx1 = 0, dy1 = 0, dz1 = 0;
    float dx2 = 0, dy2 = 0, dz2 = 0, dx3 = 0, dy3 = 0, dz3 = 0;
    if (lg == 0) {
      const float* q; const float* s;
      q = point + (unsigned)gc0 * 3u; s = point + (unsigned)sc0 * 3u;
      dx0 = q[0] - s[0]; dy0 = q[1] - s[1]; dz0 = q[2] - s[2];
      q = point + (unsigned)gc1 * 3u; s = point + (unsigned)sc1 * 3u;
      dx1 = q[0] - s[0]; dy1 = q[1] - s[1]; dz1 = q[2] - s[2];
      q = point + (unsigned)gc2 * 3u; s = point + (unsigned)sc2 * 3u;
      dx2 = q[0] - s[0]; dy2 = q[1] - s[1]; dz2 = q[2] - s[2];
      q = point + (unsigned)gc3 * 3u; s = point + (unsigned)sc3 * 3u;
      dx3 = q[0] - s[0]; dy3 = q[1] - s[1]; dz3 = q[2] - s[2];
    }

    // ---- prefetch next tile's indices (breaks idx->gather chain) ----
    int gn0 = 0, gn1 = 0, gn2 = 0, gn3 = 0, sn0 = 0, sn1 = 0, sn2 = 0, sn3 = 0;
    const int tn = t + G;
    if (tn < nTiles) {
      gn0 = knn_idx[tn * 64 +  0 + l15];
      gn1 = knn_idx[tn * 64 + 16 + l15];
      gn2 = knn_idx[tn * 64 + 32 + l15];
      gn3 = knn_idx[tn * 64 + 48 + l15];
      sn0 = sample_idx[tn * 4 + 0]; sn1 = sample_idx[tn * 4 + 1];
      sn2 = sample_idx[tn * 4 + 2]; sn3 = sample_idx[tn * 4 + 3];
    }

    float mx0_[4], mx1_[4], mn0_[4], mn1_[4];

    // ---- per point: 6 MFMAs + row-reduce (acc live only within its mi) ----
#define DOMI(MI, F0, F1, DX, DY, DZ)                                           \
    {                                                                          \
      uint4v az = {0u, 0u, 0u, 0u};                                            \
      if (lg == 0) { az[0] = pk2(DX, DY); az[1] = pk2(DZ, 0.f); }              \
      short8v a0 = __builtin_bit_cast(short8v, F0);                            \
      short8v a1 = __builtin_bit_cast(short8v, F1);                            \
      short8v a2 = __builtin_bit_cast(short8v, az);                            \
      float4v acc0 = {0.f, 0.f, 0.f, 0.f}, acc1 = {0.f, 0.f, 0.f, 0.f};        \
      acc0 = MFMA16(a0, bfrag[0][0], acc0, 0, 0, 0);                           \
      acc0 = MFMA16(a1, bfrag[0][1], acc0, 0, 0, 0);                           \
      acc0 = MFMA16(a2, bfrag[0][2], acc0, 0, 0, 0);                           \
      acc1 = MFMA16(a0, bfrag[1][0], acc1, 0, 0, 0);                           \
      acc1 = MFMA16(a1, bfrag[1][1], acc1, 0, 0, 0);                           \
      acc1 = MFMA16(a2, bfrag[1][2], acc1, 0, 0, 0);                           \
      float s_ = (acc0[0] + acc0[1]) + (acc0[2] + acc0[3]);                    \
      float q_ = fmaf(acc0[0], acc0[0], fmaf(acc0[1], acc0[1],                 \
                 fmaf(acc0[2], acc0[2], acc0[3] * acc0[3])));                  \
      sum0 += s_; sq0 += q_;                                                   \
      float mxa = fmaxf(fmaxf(acc0[0], acc0[1]), fmaxf(acc0[2], acc0[3]));     \
      mxa = fmaxf(mxa, __shfl_xor(mxa, 16));                                   \
      mxa = fmaxf(mxa, __shfl_xor(mxa, 32));                                   \
      mx0_[MI] = mxa;                                                          \
      float s2_ = (acc1[0] + acc1[1]) + (acc1[2] + acc1[3]);                   \
      float q2_ = fmaf(acc1[0], acc1[0], fmaf(acc1[1], acc1[1],                \
                  fmaf(acc1[2], acc1[2], acc1[3] * acc1[3])));                 \
      sum1 += s2_; sq1 += q2_;                                                 \
      float mxb = fmaxf(fmaxf(acc1[0], acc1[1]), fmaxf(acc1[2], acc1[3]));     \
      mxb = fmaxf(mxb, __shfl_xor(mxb, 16));                                   \
      mxb = fmaxf(mxb, __shfl_xor(mxb, 32));                                   \
      mx1_[MI] = mxb;                                                          \
      if (do_min) {                                                            \
        float mna = fminf(fminf(acc0[0], acc0[1]), fminf(acc0[2], acc0[3]));   \
        mna = fminf(mna, __shfl_xor(mna, 16));                                 \
        mna = fminf(mna, __shfl_xor(mna, 32));                                 \
        mn0_[MI] = mna;                                                        \
        float mnb = fminf(fminf(acc1[0], acc1[1]), fminf(acc1[2], acc1[3]));   \
        mnb = fminf(mnb, __shfl_xor(mnb, 16));                                 \
        mnb = fminf(mnb, __shfl_xor(mnb, 32));                                 \
        mn1_[MI] = mnb;                                                        \
      }                                                                        \
    }
    DOMI(0, f00, f10, dx0, dy0, dz0)
    DOMI(1, f01, f11, dx1, dy1, dz1)
    DOMI(2, f02, f12, dx2, dy2, dz2)
    DOMI(3, f03, f13, dx3, dy3, dz3)
#undef DOMI

    // all-64-lane stores: lane group lg writes point t*4+lg (static selects)
    {
      float vx0 = lg == 0 ? mx0_[0] : lg == 1 ? mx0_[1] : lg == 2 ? mx0_[2] : mx0_[3];
      float vx1 = lg == 0 ? mx1_[0] : lg == 1 ? mx1_[1] : lg == 2 ? mx1_[2] : mx1_[3];
      size_t ob = (size_t)(t * 4 + lg) * 128 + wv * 32 + l15;
      ymax_out[ob]      = vx0;
      ymax_out[ob + 16] = vx1;
      if (do_min) {
        float vn0 = lg == 0 ? mn0_[0] : lg == 1 ? mn0_[1] : lg == 2 ? mn0_[2] : mn0_[3];
        float vn1 = lg == 0 ? mn1_[0] : lg == 1 ? mn1_[1] : lg == 2 ? mn1_[2] : mn1_[3];
        if (gva < 0.f) ymin_out[ob]      = vn0;
        if (gvb < 0.f) ymin_out[ob + 16] = vn1;
      }
    }

    gc0 = gn0; gc1 = gn1; gc2 = gn2; gc3 = gn3;
    sc0 = sn0; sc1 = sn1; sc2 = sn2; sc3 = sn3;
  }

  // deterministic per-block partials (channels disjoint per wave -> no sync)
  sum0 += __shfl_xor(sum0, 16); sum0 += __shfl_xor(sum0, 32);
  sq0  += __shfl_xor(sq0, 16);  sq0  += __shfl_xor(sq0, 32);
  sum1 += __shfl_xor(sum1, 16); sum1 += __shfl_xor(sum1, 32);
  sq1  += __shfl_xor(sq1, 16);  sq1  += __shfl_xor(sq1, 32);
  if ((lane & 63) < 16) {
    float* pp = partials + (size_t)blockIdx.x * 256;
    pp[wv * 32 + l15]            = sum0;
    pp[128 + wv * 32 + l15]      = sq0;
    pp[wv * 32 + 16 + l15]       = sum1;
    pp[128 + wv * 32 + 16 + l15] = sq1;
  }
}

// Parallel BN-stats fold: one block per channel.
__global__ __launch_bounds__(256) void td_stats(
    const float* __restrict__ partials,
    const float* __restrict__ gamma,
    const float* __restrict__ beta,
    float* __restrict__ ab, int G, float invN)
{
  __shared__ float ls[256], lq[256];
  const int d = blockIdx.x;
  const int t = threadIdx.x;
  float s = 0.f, q = 0.f;
  for (int g = t; g < G; g += 256) {
    s += partials[(size_t)g * 256 + d];
    q += partials[(size_t)g * 256 + 128 + d];
  }
  ls[t] = s; lq[t] = q;
  __syncthreads();
  for (int w = 128; w > 0; w >>= 1) {
    if (t < w) { ls[t] += ls[t + w]; lq[t] += lq[t + w]; }
    __syncthreads();
  }
  if (t == 0) {
    float mean = ls[0] * invN;
    float var  = fmaxf(lq[0] * invN - mean * mean, 0.f);
    float a = gamma[d] * rsqrtf(var + 1e-5f);
    float bb = beta[d] - mean * a;
    ab[d] = a;
    ab[128 + d] = bb;
  }
}

__global__ __launch_bounds__(256) void td_transform(
    float* __restrict__ outf, const float* __restrict__ ymin,
    const float* __restrict__ ab, int total4, int has_ymin)
{
  __shared__ float sab[256];
  __shared__ int s_anyneg;
  sab[threadIdx.x] = ab[threadIdx.x];
  if (threadIdx.x == 0) s_anyneg = 0;
  __syncthreads();
  if (threadIdx.x < 128 && sab[threadIdx.x] < 0.f) s_anyneg = 1;
  __syncthreads();
  const int need_min = has_ymin && s_anyneg;
  int stride = gridDim.x * blockDim.x;
  for (int i = blockIdx.x * blockDim.x + threadIdx.x; i < total4; i += stride) {
    float4v v = *(const float4v*)(outf + (size_t)i * 4);
    int d0 = (i * 4) & 127;
    if (need_min) {
      float4v mn = *(const float4v*)(ymin + (size_t)i * 4);
      #pragma unroll
      for (int j = 0; j < 4; ++j)
        if (sab[d0 + j] < 0.f) v[j] = mn[j];
    }
    #pragma unroll
    for (int j = 0; j < 4; ++j) {
      float z = fmaf(v[j], sab[d0 + j], sab[128 + d0 + j]);
      v[j] = z > 0.f ? z : 0.f;
    }
    *(float4v*)(outf + (size_t)i * 4) = v;
  }
}

extern "C" void kernel_launch(void* const* d_in, const int* in_sizes, int n_in,
                              void* d_out, int out_size, void* d_ws, size_t ws_size,
                              hipStream_t stream)
{
  const float* point = (const float*)d_in[0];
  const float* feat  = (const float*)d_in[1];
  const float* W     = (const float*)d_in[2];
  const float* gamma = (const float*)d_in[3];
  const float* beta  = (const float*)d_in[4];
  const int* sample_idx = (const int*)d_in[5];
  const int* knn_idx    = (const int*)d_in[6];

  const int m = in_sizes[5];            // 60000
  const int k = in_sizes[6] / m;        // 16
  const int nTiles = m / 4;
  const int feat_elems = in_sizes[1];   // n * 64

  float* out  = (float*)d_out;
  float* newp = out;                    // (m,3)
  float* ymax = out + (size_t)m * 3;    // (m,128)

  int G = (nTiles + 7) / 8;             // 8 tiles/block; 1875 <= 2048 capacity
  if (G > 2048) G = 2048;
  if (G < 1) G = 1;

  // ws layout: [ab 1KB][partials G*1KB][feat_bf16][ymin if it fits]
  char* ws = (char*)d_ws;
  float* ab = (float*)ws;
  float* partials = (float*)(ws + 1024);
  size_t fb_off = 1024 + (size_t)G * 1024;
  size_t fb_bytes = (size_t)feat_elems * 2;
  int use_fb = (ws_size >= fb_off + fb_bytes) ? 1 : 0;
  unsigned short* fb = (unsigned short*)(ws + fb_off);
  size_t ymin_off = fb_off + (use_fb ? fb_bytes : 0);
  int has_ymin = (ws_size >= ymin_off + (size_t)m * 512) ? 1 : 0;
  float* ymin = (float*)(ws + ymin_off);

  {
    int total8 = use_fb ? feat_elems / 8 : 0;
    int prepBlocks = (total8 + 255) / 256;
    int npBlocks = (m + 255) / 256;
    td_prep<<<prepBlocks + npBlocks, 256, 0, stream>>>(
        feat, fb, total8, point, sample_idx, newp, m, prepBlocks);
  }
  td_main<<<G, 256, 0, stream>>>(point, feat, fb, W, gamma, sample_idx, knn_idx,
                                 ymax, ymin, partials, nTiles, has_ymin, use_fb);
  float invN = 1.0f / ((float)m * (float)k);
  td_stats<<<128, 256, 0, stream>>>(partials, gamma, beta, ab, G, invN);
  td_transform<<<2048, 256, 0, stream>>>(ymax, ymin, ab, m * 128 / 4, has_ymin);
}

// Round 14
// 108.495 us; speedup vs baseline: 3.3035x; 3.3035x over previous
//
#include <hip/hip_runtime.h>
#include <hip/hip_bf16.h>

typedef __attribute__((ext_vector_type(4))) float float4v;
typedef __attribute__((ext_vector_type(8))) short short8v;
typedef __attribute__((ext_vector_type(4))) unsigned int uint4v;

__device__ __forceinline__ unsigned short f2bf(float f) {
  __hip_bfloat16 h = __float2bfloat16(f);   // HW RNE cvt
  return __builtin_bit_cast(unsigned short, h);
}
__device__ __forceinline__ unsigned int pk2(float a, float b) {
  return (unsigned int)f2bf(a) | ((unsigned int)f2bf(b) << 16);
}

// Fused one-time pass: feat f32 -> bf16 table (halves gather bytes) + new_point copy.
__global__ __launch_bounds__(256) void td_prep(const float* __restrict__ feat,
                                               unsigned short* __restrict__ fb,
                                               int total8,
                                               const float* __restrict__ point,
                                               const int* __restrict__ sidx,
                                               float* __restrict__ newp, int m,
                                               int prepBlocks) {
  if ((int)blockIdx.x < prepBlocks) {
    int i = blockIdx.x * 256 + threadIdx.x;
    if (i < total8) {
      const float4v a = *(const float4v*)(feat + (size_t)i * 8);
      const float4v c = *(const float4v*)(feat + (size_t)i * 8 + 4);
      uint4v u;
      u[0] = pk2(a[0], a[1]); u[1] = pk2(a[2], a[3]);
      u[2] = pk2(c[0], c[1]); u[3] = pk2(c[2], c[3]);
      *(uint4v*)(fb + (size_t)i * 8) = u;
    }
  } else {
    int i = (blockIdx.x - prepBlocks) * 256 + threadIdx.x;
    if (i < m) {
      unsigned s = (unsigned)sidx[i];
      newp[(size_t)i * 3 + 0] = point[s * 3u + 0];
      newp[(size_t)i * 3 + 1] = point[s * 3u + 1];
      newp[(size_t)i * 3 + 2] = point[s * 3u + 2];
    }
  }
}

// td_main: R6 structure (best clean: 63us, WRITE=logical). tile = 4 sampled
// points (64 rows) x K=96. Register software-pipeline: tile t+1's gathers
// issued at top of iter t from the bf16 table, parked in regs across
// MFMA+epilogue, written to LDS after B2.
// Occupancy map (measured): (256,4) 96 regs fit; (256,6) budget 85 -> spill;
// (256,8) budget 64 -> heavy spill. (256,5) budget ~102 >= 96: this round.
__global__ __launch_bounds__(256, 5) void td_main(
    const float* __restrict__ point, const float* __restrict__ feat,
    const unsigned short* __restrict__ fb, const float* __restrict__ W,
    const float* __restrict__ gamma,
    const int* __restrict__ sample_idx, const int* __restrict__ knn_idx,
    float* __restrict__ ymax_out, float* __restrict__ ymin_out,
    float* __restrict__ partials, int nTiles, int has_ymin, int use_fb)
{
  __shared__ __align__(16) unsigned short A[64 * 104];   // 13312 B
  __shared__ int knn_lds[2][64];

  const int tid  = threadIdx.x;
  const int lane = tid & 63;
  const int wv   = tid >> 6;        // wave -> output channels wv*32..+31
  const int l15  = lane & 15;
  const int lg   = lane >> 4;
  const int G    = gridDim.x;
  const int t0   = blockIdx.x;
  const int segs = (tid & 3) << 4;  // element offset of this thread's 16-elem segment

  // One-time: B fragments direct from global W (bf16-rounded), permuted K.
  short8v bfrag[2][3];
  #pragma unroll
  for (int ni = 0; ni < 2; ++ni) {
    const int d = wv * 32 + ni * 16 + l15;
    #pragma unroll
    for (int kk = 0; kk < 3; ++kk) {
      short8v bf;
      #pragma unroll
      for (int j = 0; j < 8; ++j) {
        int c = kk * 32 + (lg << 3) + j;
        float v = 0.f;
        if (c < 64)      v = W[(3 + c) * 128 + d];
        else if (c < 67) v = W[(c - 64) * 128 + d];
        bf[j] = (short)f2bf(v);
      }
      bfrag[ni][kk] = bf;
    }
  }
  // min-path only needed for channels with gamma<0 (sign(a)==sign(gamma))
  const float gva = gamma[wv * 32 + l15];
  const float gvb = gamma[wv * 32 + 16 + l15];
  const bool  do_min = has_ymin && (__ballot((gva < 0.f) || (gvb < 0.f)) != 0ull);

  const bool alive = (t0 < nTiles);
  if (alive && tid < 64) knn_lds[0][tid] = knn_idx[t0 * 64 + tid];
  __syncthreads();

  // pipeline registers
  uint4v h0 = {0,0,0,0}, h1 = {0,0,0,0};
  float qx = 0, qy = 0, qz = 0, sx = 0, sy = 0, sz = 0;
  int   si_a = 0, knn_next = 0;

  // tile t0 loads (dependent chain once, in prologue)
  if (alive) {
    const int grow = knn_lds[0][tid >> 2];
    if (use_fb) {
      const uint4v* src = (const uint4v*)(fb + ((size_t)grow << 6) + segs);
      h0 = src[0]; h1 = src[1];
    } else {
      const float* srcf = feat + ((size_t)grow << 6) + segs;
      float4v f0 = *(const float4v*)(srcf),     f1 = *(const float4v*)(srcf + 4);
      float4v f2 = *(const float4v*)(srcf + 8), f3 = *(const float4v*)(srcf + 12);
      h0[0] = pk2(f0[0], f0[1]); h0[1] = pk2(f0[2], f0[3]);
      h0[2] = pk2(f1[0], f1[1]); h0[3] = pk2(f1[2], f1[3]);
      h1[0] = pk2(f2[0], f2[1]); h1[1] = pk2(f2[2], f2[3]);
      h1[2] = pk2(f3[0], f3[1]); h1[3] = pk2(f3[2], f3[3]);
    }
    if (tid < 64) {
      const float* ps = point + (unsigned)knn_lds[0][tid] * 3u;
      qx = ps[0]; qy = ps[1]; qz = ps[2];
      int si = sample_idx[t0 * 4 + (tid >> 4)];
      const float* pp2 = point + (unsigned)si * 3u;
      sx = pp2[0]; sy = pp2[1]; sz = pp2[2];
    }
  }
  if (t0 + G < nTiles && tid < 64) {
    knn_lds[1][tid] = knn_idx[(t0 + G) * 64 + tid];
    si_a = sample_idx[(t0 + G) * 4 + (tid >> 4)];
  }

  // write A[t0] (incl. one-time zero of cols 72..95)
  if (alive) {
    unsigned short* dst = A + (tid >> 2) * 104 + segs;
    *(uint4v*)(dst)     = h0;
    *(uint4v*)(dst + 8) = h1;
    if (tid < 64) {
      uint4v u; u[0] = pk2(qx - sx, qy - sy); u[1] = pk2(qz - sz, 0.f);
      u[2] = 0u; u[3] = 0u;
      unsigned short* dx = A + tid * 104 + 64;
      *(uint4v*)(dx) = u;                         // cols 64..71
      uint4v zz = {0u, 0u, 0u, 0u};
      *(uint4v*)(dx + 8)  = zz;                   // cols 72..95: once
      *(uint4v*)(dx + 16) = zz;
      *(uint4v*)(dx + 24) = zz;
    }
  }

  float sum0 = 0.f, sum1 = 0.f, sq0 = 0.f, sq1 = 0.f;

  int b = 0;
  for (int t = t0; t < nTiles; t += G, b ^= 1) {
    __syncthreads();   // B1: A[t] ready; knn[b^1] (tile t+G) visible
    const int tn  = t + G;
    const int tnn = t + 2 * G;
    const bool have_next = (tn < nTiles);

    // issue tile t+1 loads into regs (fly across MFMA + epilogue)
    if (have_next) {
      const int grow = knn_lds[b ^ 1][tid >> 2];
      if (use_fb) {
        const uint4v* src = (const uint4v*)(fb + ((size_t)grow << 6) + segs);
        h0 = src[0]; h1 = src[1];
      } else {
        const float* srcf = feat + ((size_t)grow << 6) + segs;
        float4v f0 = *(const float4v*)(srcf),     f1 = *(const float4v*)(srcf + 4);
        float4v f2 = *(const float4v*)(srcf + 8), f3 = *(const float4v*)(srcf + 12);
        h0[0] = pk2(f0[0], f0[1]); h0[1] = pk2(f0[2], f0[3]);
        h0[2] = pk2(f1[0], f1[1]); h0[3] = pk2(f1[2], f1[3]);
        h1[0] = pk2(f2[0], f2[1]); h1[1] = pk2(f2[2], f2[3]);
        h1[2] = pk2(f3[0], f3[1]); h1[3] = pk2(f3[2], f3[3]);
      }
      if (tid < 64) {
        const float* ps = point + (unsigned)knn_lds[b ^ 1][tid] * 3u;
        qx = ps[0]; qy = ps[1]; qz = ps[2];
        const float* pp2 = point + (unsigned)si_a * 3u;  // si_a from last iter
        sx = pp2[0]; sy = pp2[1]; sz = pp2[2];
      }
    }
    // issue tile t+2 index loads
    if (tnn < nTiles && tid < 64) {
      knn_next = knn_idx[tnn * 64 + tid];
      si_a = sample_idx[tnn * 4 + (tid >> 4)];
    }

    // MFMA on A[t]
    float4v acc[4][2];
    #pragma unroll
    for (int mi = 0; mi < 4; ++mi) {
      acc[mi][0] = (float4v){0.f, 0.f, 0.f, 0.f};
      acc[mi][1] = (float4v){0.f, 0.f, 0.f, 0.f};
    }
    #pragma unroll
    for (int mi = 0; mi < 4; ++mi) {
      const unsigned short* ar = A + (mi * 16 + l15) * 104 + (lg << 3);
      short8v a0 = *(const short8v*)(ar);
      short8v a1 = *(const short8v*)(ar + 32);
      short8v a2 = *(const short8v*)(ar + 64);
      #pragma unroll
      for (int ni = 0; ni < 2; ++ni) {
        acc[mi][ni] = __builtin_amdgcn_mfma_f32_16x16x32_bf16(a0, bfrag[ni][0], acc[mi][ni], 0, 0, 0);
        acc[mi][ni] = __builtin_amdgcn_mfma_f32_16x16x32_bf16(a1, bfrag[ni][1], acc[mi][ni], 0, 0, 0);
        acc[mi][ni] = __builtin_amdgcn_mfma_f32_16x16x32_bf16(a2, bfrag[ni][2], acc[mi][ni], 0, 0, 0);
      }
    }

    // epilogue: stats + per-point max (min only if some gamma<0)
    float mx0[4], mx1[4], mn0[4], mn1[4];
    #pragma unroll
    for (int mi = 0; mi < 4; ++mi) {
      #pragma unroll
      for (int ni = 0; ni < 2; ++ni) {
        float4v v = acc[mi][ni];
        float s = (v[0] + v[1]) + (v[2] + v[3]);
        float q = fmaf(v[0], v[0], fmaf(v[1], v[1], fmaf(v[2], v[2], v[3] * v[3])));
        if (ni == 0) { sum0 += s; sq0 += q; } else { sum1 += s; sq1 += q; }
        float mx = fmaxf(fmaxf(v[0], v[1]), fmaxf(v[2], v[3]));
        mx = fmaxf(mx, __shfl_xor(mx, 16)); mx = fmaxf(mx, __shfl_xor(mx, 32));
        if (ni == 0) mx0[mi] = mx; else mx1[mi] = mx;
        if (do_min) {
          float mn = fminf(fminf(v[0], v[1]), fminf(v[2], v[3]));
          mn = fminf(mn, __shfl_xor(mn, 16)); mn = fminf(mn, __shfl_xor(mn, 32));
          if (ni == 0) mn0[mi] = mn; else mn1[mi] = mn;
        }
      }
    }
    {
      float vx0 = lg == 0 ? mx0[0] : lg == 1 ? mx0[1] : lg == 2 ? mx0[2] : mx0[3];
      float vx1 = lg == 0 ? mx1[0] : lg == 1 ? mx1[1] : lg == 2 ? mx1[2] : mx1[3];
      size_t obase = (size_t)(t * 4 + lg) * 128 + wv * 32 + l15;
      ymax_out[obase]      = vx0;
      ymax_out[obase + 16] = vx1;
      if (do_min) {
        float vn0 = lg == 0 ? mn0[0] : lg == 1 ? mn0[1] : lg == 2 ? mn0[2] : mn0[3];
        float vn1 = lg == 0 ? mn1[0] : lg == 1 ? mn1[1] : lg == 2 ? mn1[2] : mn1[3];
        if (gva < 0.f) ymin_out[obase]      = vn0;
        if (gvb < 0.f) ymin_out[obase + 16] = vn1;
      }
    }
    // park prefetched knn for t+2 (loads long completed)
    if (tnn < nTiles && tid < 64) knn_lds[b][tid] = knn_next;
    __syncthreads();   // B2: A[t] consumed

    // write A[t+1] from in-flight regs (cols 0..71; 72..95 stay zero)
    if (have_next) {
      unsigned short* dst = A + (tid >> 2) * 104 + segs;
      *(uint4v*)(dst)     = h0;
      *(uint4v*)(dst + 8) = h1;
      if (tid < 64) {
        uint4v u; u[0] = pk2(qx - sx, qy - sy); u[1] = pk2(qz - sz, 0.f);
        u[2] = 0u; u[3] = 0u;
        *(uint4v*)(A + tid * 104 + 64) = u;
      }
    }
  }

  // deterministic per-block partials
  sum0 += __shfl_xor(sum0, 16); sum0 += __shfl_xor(sum0, 32);
  sq0  += __shfl_xor(sq0, 16);  sq0  += __shfl_xor(sq0, 32);
  sum1 += __shfl_xor(sum1, 16); sum1 += __shfl_xor(sum1, 32);
  sq1  += __shfl_xor(sq1, 16);  sq1  += __shfl_xor(sq1, 32);
  if (lane < 16) {
    float* pp = partials + (size_t)blockIdx.x * 256;
    pp[wv * 32 + lane]            = sum0;
    pp[128 + wv * 32 + lane]      = sq0;
    pp[wv * 32 + 16 + lane]       = sum1;
    pp[128 + wv * 32 + 16 + lane] = sq1;
  }
}

// Parallel BN-stats fold: one block per channel.
__global__ __launch_bounds__(256) void td_stats(
    const float* __restrict__ partials,
    const float* __restrict__ gamma,
    const float* __restrict__ beta,
    float* __restrict__ ab, int G, float invN)
{
  __shared__ float ls[256], lq[256];
  const int d = blockIdx.x;
  const int t = threadIdx.x;
  float s = 0.f, q = 0.f;
  for (int g = t; g < G; g += 256) {
    s += partials[(size_t)g * 256 + d];
    q += partials[(size_t)g * 256 + 128 + d];
  }
  ls[t] = s; lq[t] = q;
  __syncthreads();
  for (int w = 128; w > 0; w >>= 1) {
    if (t < w) { ls[t] += ls[t + w]; lq[t] += lq[t + w]; }
    __syncthreads();
  }
  if (t == 0) {
    float mean = ls[0] * invN;
    float var  = fmaxf(lq[0] * invN - mean * mean, 0.f);
    float a = gamma[d] * rsqrtf(var + 1e-5f);
    float bb = beta[d] - mean * a;
    ab[d] = a;
    ab[128 + d] = bb;
  }
}

__global__ __launch_bounds__(256) void td_transform(
    float* __restrict__ outf, const float* __restrict__ ymin,
    const float* __restrict__ ab, int total4, int has_ymin)
{
  __shared__ float sab[256];
  __shared__ int s_anyneg;
  sab[threadIdx.x] = ab[threadIdx.x];
  if (threadIdx.x == 0) s_anyneg = 0;
  __syncthreads();
  if (threadIdx.x < 128 && sab[threadIdx.x] < 0.f) s_anyneg = 1;
  __syncthreads();
  const int need_min = has_ymin && s_anyneg;
  int stride = gridDim.x * blockDim.x;
  for (int i = blockIdx.x * blockDim.x + threadIdx.x; i < total4; i += stride) {
    float4v v = *(const float4v*)(outf + (size_t)i * 4);
    int d0 = (i * 4) & 127;
    if (need_min) {
      float4v mn = *(const float4v*)(ymin + (size_t)i * 4);
      #pragma unroll
      for (int j = 0; j < 4; ++j)
        if (sab[d0 + j] < 0.f) v[j] = mn[j];
    }
    #pragma unroll
    for (int j = 0; j < 4; ++j) {
      float z = fmaf(v[j], sab[d0 + j], sab[128 + d0 + j]);
      v[j] = z > 0.f ? z : 0.f;
    }
    *(float4v*)(outf + (size_t)i * 4) = v;
  }
}

extern "C" void kernel_launch(void* const* d_in, const int* in_sizes, int n_in,
                              void* d_out, int out_size, void* d_ws, size_t ws_size,
                              hipStream_t stream)
{
  const float* point = (const float*)d_in[0];
  const float* feat  = (const float*)d_in[1];
  const float* W     = (const float*)d_in[2];
  const float* gamma = (const float*)d_in[3];
  const float* beta  = (const float*)d_in[4];
  const int* sample_idx = (const int*)d_in[5];
  const int* knn_idx    = (const int*)d_in[6];

  const int m = in_sizes[5];            // 60000
  const int k = in_sizes[6] / m;        // 16
  const int nTiles = m / 4;             // 4 points (64 rows) per tile
  const int feat_elems = in_sizes[1];   // n * 64

  float* out  = (float*)d_out;
  float* newp = out;                    // (m,3)
  float* ymax = out + (size_t)m * 3;    // (m,128) pre-norm max, finished in-place

  // 12 tiles/block -> G=1250 for m=60000: one resident generation at
  // 5 blocks/CU (capacity 1280), divides nTiles exactly (uniform work).
  int G = (nTiles + 11) / 12;
  if (G > 1280) G = 1280;
  if (G < 1) G = 1;

  // ws layout: [ab 1KB][partials G*1KB][feat_bf16][ymin if it fits]
  char* ws = (char*)d_ws;
  float* ab = (float*)ws;
  float* partials = (float*)(ws + 1024);
  size_t fb_off = 1024 + (size_t)G * 1024;
  size_t fb_bytes = (size_t)feat_elems * 2;
  int use_fb = (ws_size >= fb_off + fb_bytes) ? 1 : 0;
  unsigned short* fb = (unsigned short*)(ws + fb_off);
  size_t ymin_off = fb_off + (use_fb ? fb_bytes : 0);
  int has_ymin = (ws_size >= ymin_off + (size_t)m * 512) ? 1 : 0;
  float* ymin = (float*)(ws + ymin_off);

  {
    int total8 = use_fb ? feat_elems / 8 : 0;
    int prepBlocks = (total8 + 255) / 256;
    int npBlocks = (m + 255) / 256;
    td_prep<<<prepBlocks + npBlocks, 256, 0, stream>>>(
        feat, fb, total8, point, sample_idx, newp, m, prepBlocks);
  }
  td_main<<<G, 256, 0, stream>>>(point, feat, fb, W, gamma, sample_idx, knn_idx,
                                 ymax, ymin, partials, nTiles, has_ymin, use_fb);
  float invN = 1.0f / ((float)m * (float)k);
  td_stats<<<128, 256, 0, stream>>>(partials, gamma, beta, ab, G, invN);
  td_transform<<<2048, 256, 0, stream>>>(ymax, ymin, ab, m * 128 / 4, has_ymin);
}